// Round 1
// baseline (240.124 us; speedup 1.0000x reference)
//
#include <hip/hip_runtime.h>

#define BB 16
#define SS 256
#define CC 17
#define NCH 16
#define DD 32
#define DFF 64
#define HH 4
#define DH 8
#define EE 4
#define NF 129   // rfft bins for n=256

// ws layout (in floats):
//  [0]=bmin [1]=bmax
//  [16  .. 143]  K0[e][d]   (4*32)
//  [144 .. 271]  V0[e][d]   (4*32)
//  [512 .. 512+65535]  XNS[b][s][n]  (B*S*NCH)
//  ints at [66048 ..]: SP[b][t] sorted positions (4096), then OFF[b][e] (64)
#define WS_K0 16
#define WS_V0 144
#define WS_XNS 512
#define WS_SPI (WS_XNS + BB*SS*NCH)   // 66048 (int index)

// ---------------------------------------------------------------------------
// Kernel 1: seasonal-trend decomposition per (b, channel n<16)
// ---------------------------------------------------------------------------
__global__ void decomp_kernel(const float* __restrict__ x, float* __restrict__ ws) {
  const int b = blockIdx.x / NCH;
  const int c = blockIdx.x % NCH;
  const int t = threadIdx.x;  // 256
  __shared__ float xs[SS];
  __shared__ float ct[SS];
  __shared__ float Xr[NF], Xi[NF], amp[NF];
  __shared__ float thr;
  xs[t] = x[(b*SS + t)*CC + c];
  ct[t] = cosf((float)t * 0.024543692606170259f);  // 2*pi/256
  __syncthreads();
  if (t < NF) {
    float xr = 0.f, xi = 0.f;
    for (int s2 = 0; s2 < SS; ++s2) {
      int idx = (t * s2) & 255;
      float xv = xs[s2];
      xr += xv * ct[idx];
      xi -= xv * ct[(idx + 192) & 255];  // sin(th) = cos(th - pi/2)
    }
    Xr[t] = xr; Xi[t] = xi;
    amp[t] = sqrtf(xr*xr + xi*xi);
  }
  __syncthreads();
  if (t == 0) {
    // 4th-largest amplitude among f=1..128 (f=0 excluded: amp[0]=-inf in ref)
    int i0 = -1, i1 = -1, i2 = -1;
    float th = -1e30f;
    for (int p = 0; p < 4; ++p) {
      float best = -1e30f; int bi = -1;
      for (int f = 1; f < NF; ++f) {
        if (f == i0 || f == i1 || f == i2) continue;
        if (amp[f] > best) { best = amp[f]; bi = f; }
      }
      if (p == 0) i0 = bi; else if (p == 1) i1 = bi; else if (p == 2) i2 = bi;
      th = best;
    }
    thr = th;
  }
  __syncthreads();
  const float th = thr;
  // season: irfft of masked spectrum at s=t
  float acc = 0.f;
  for (int f = 1; f < NF; ++f) {
    if (amp[f] >= th) {
      int idx = (f * t) & 255;
      float contrib = Xr[f] * ct[idx] - Xi[f] * ct[(idx + 192) & 255];
      acc += (f == 128 ? 1.0f : 2.0f) * contrib;
    }
  }
  float season = acc * (1.0f / 256.0f);
  // trend: mean of moving averages k=4,8,12 with edge-replicate padding
  float s4 = 0.f, s8 = 0.f, s12 = 0.f;
  #pragma unroll
  for (int j = 0; j < 4; ++j)  { int p = t + j - 1; p = p < 0 ? 0 : (p > SS-1 ? SS-1 : p); s4  += xs[p]; }
  #pragma unroll
  for (int j = 0; j < 8; ++j)  { int p = t + j - 3; p = p < 0 ? 0 : (p > SS-1 ? SS-1 : p); s8  += xs[p]; }
  #pragma unroll
  for (int j = 0; j < 12; ++j) { int p = t + j - 5; p = p < 0 ? 0 : (p > SS-1 ? SS-1 : p); s12 += xs[p]; }
  float trend = (s4 * 0.25f + s8 * 0.125f + s12 * (1.0f/12.0f)) * (1.0f/3.0f);
  ws[WS_XNS + (b*SS + t)*NCH + c] = xs[t] + season + trend;
}

// ---------------------------------------------------------------------------
// Kernel 2: global min/max of scores
// ---------------------------------------------------------------------------
__global__ void minmax_kernel(const float* __restrict__ ox, float* __restrict__ ws) {
  __shared__ float smn[256], smx[256];
  int t = threadIdx.x;
  float mn = 3e38f, mx = -3e38f;
  for (int i = t; i < BB*SS; i += 256) {
    float v = ox[i*2 + 1];
    mn = fminf(mn, v); mx = fmaxf(mx, v);
  }
  smn[t] = mn; smx[t] = mx;
  __syncthreads();
  for (int off = 128; off > 0; off >>= 1) {
    if (t < off) { smn[t] = fminf(smn[t], smn[t+off]); smx[t] = fmaxf(smx[t], smx[t+off]); }
    __syncthreads();
  }
  if (t == 0) { ws[0] = smn[0]; ws[1] = smx[0]; }
}

// ---------------------------------------------------------------------------
// Kernel 3: expert assignment + expert-sorted position lists per b
// ---------------------------------------------------------------------------
__global__ void assign_kernel(const float* __restrict__ ox, float* __restrict__ ws) {
  int b = blockIdx.x, t = threadIdx.x;
  __shared__ int asg[SS];
  __shared__ int cnt[EE], offs[EE];
  float bmin = ws[0], bmax = ws[1];
  float step = (bmax - bmin) * 0.25f;
  float e1 = bmin + step, e2 = bmin + step*2.0f, e3 = bmin + step*3.0f;
  float sc = ox[(b*SS + t)*2 + 1];
  // searchsorted(bins, sc, 'right') - 1, clipped to [0,3]
  int a = (sc >= e1) + (sc >= e2) + (sc >= e3);
  asg[t] = a;
  __syncthreads();
  if (t < EE) {
    int c = 0;
    for (int s2 = 0; s2 < SS; ++s2) c += (asg[s2] == t);
    cnt[t] = c;
  }
  __syncthreads();
  if (t == 0) { int o = 0; for (int e = 0; e < EE; ++e) { offs[e] = o; o += cnt[e]; } }
  __syncthreads();
  int* SP  = (int*)ws + WS_SPI;
  int* OFF = SP + BB*SS;
  if (t < EE) {
    int kp = offs[t];
    for (int s2 = 0; s2 < SS; ++s2) if (asg[s2] == t) SP[b*SS + (kp++)] = s2;
    OFF[b*4 + t] = offs[t];
  }
}

// ---------------------------------------------------------------------------
// Kernel 4: per-expert k0/v0 of the constant (unassigned) hidden = start_b
// ---------------------------------------------------------------------------
__global__ void k0v0_kernel(const float* __restrict__ sb, const float* __restrict__ g1,
                            const float* __restrict__ bb1, const float* __restrict__ Wk,
                            const float* __restrict__ Wv, float* __restrict__ ws) {
  int t = threadIdx.x;  // 128
  int e = t >> 5, d = t & 31;
  __shared__ float z0[EE][DD];
  float m = 0.f;
  for (int i = 0; i < DD; ++i) m += sb[i];
  m *= (1.0f/DD);
  float var = 0.f;
  for (int i = 0; i < DD; ++i) { float df = sb[i]-m; var += df*df; }
  var *= (1.0f/DD);
  float rs = rsqrtf(var + 1e-5f);
  z0[e][d] = (sb[d]-m)*rs*g1[e*DD+d] + bb1[e*DD+d];
  __syncthreads();
  float k0 = 0.f, v0 = 0.f;
  for (int i = 0; i < DD; ++i) {
    float zz = z0[e][i];
    k0 += zz * Wk[e*DD*DD + i*DD + d];
    v0 += zz * Wv[e*DD*DD + i*DD + d];
  }
  ws[WS_K0 + e*DD + d] = k0;
  ws[WS_V0 + e*DD + d] = v0;
}

// ---------------------------------------------------------------------------
// Kernel 5: fused expert forward, one block per (b, n), thread = sorted pos
// ---------------------------------------------------------------------------
__device__ __forceinline__ void matvec32(float* acc, const float* vec, const float* __restrict__ Wm) {
  #pragma unroll
  for (int d = 0; d < DD; ++d) acc[d] = 0.f;
  #pragma unroll
  for (int i = 0; i < DD; ++i) {
    float zz = vec[i];
    const float4* row = (const float4*)(Wm + i*DD);
    #pragma unroll
    for (int d4 = 0; d4 < 8; ++d4) {
      float4 w = row[d4];
      acc[d4*4+0] += zz*w.x; acc[d4*4+1] += zz*w.y;
      acc[d4*4+2] += zz*w.z; acc[d4*4+3] += zz*w.w;
    }
  }
}

__launch_bounds__(256, 1)
__global__ void expert_kernel(const float* __restrict__ ws,
    const float* __restrict__ sW, const float* __restrict__ sb,
    const float* __restrict__ Wq, const float* __restrict__ Wk,
    const float* __restrict__ Wv, const float* __restrict__ Wo,
    const float* __restrict__ g1, const float* __restrict__ bb1,
    const float* __restrict__ g2, const float* __restrict__ bb2,
    const float* __restrict__ W1, const float* __restrict__ b1,
    const float* __restrict__ W2, const float* __restrict__ b2,
    float* __restrict__ out) {
  const int b = blockIdx.x / NCH;
  const int n = blockIdx.x % NCH;
  const int t = threadIdx.x;
  __shared__ float kls[SS*DD];   // 32 KB
  __shared__ float vls[SS*DD];   // 32 KB
  const int* SP  = (const int*)ws + WS_SPI;
  const int* OFF = SP + BB*SS;
  const int o1 = OFF[b*4+1], o2 = OFF[b*4+2], o3 = OFF[b*4+3];
  const int e = (t >= o1) + (t >= o2) + (t >= o3);
  const int beg = (e==0) ? 0  : ((e==1) ? o1 : ((e==2) ? o2 : o3));
  const int end = (e==0) ? o1 : ((e==1) ? o2 : ((e==2) ? o3 : SS));
  const int s = SP[b*SS + t];
  const float xv = ws[WS_XNS + (b*SS + s)*NCH + n];

  float h[DD];
  #pragma unroll
  for (int d = 0; d < DD; ++d) h[d] = xv * sW[d] + sb[d];

  // LN1
  float m = 0.f;
  #pragma unroll
  for (int d = 0; d < DD; ++d) m += h[d];
  m *= (1.0f/DD);
  float var = 0.f;
  #pragma unroll
  for (int d = 0; d < DD; ++d) { float df = h[d]-m; var += df*df; }
  var *= (1.0f/DD);
  float rs = rsqrtf(var + 1e-5f);
  float z[DD];
  #pragma unroll
  for (int d = 0; d < DD; ++d) z[d] = (h[d]-m)*rs*g1[e*DD+d] + bb1[e*DD+d];

  float tmp[DD];
  matvec32(tmp, z, Wk + e*DD*DD);
  #pragma unroll
  for (int d = 0; d < DD; ++d) kls[t*DD + d] = tmp[d];
  matvec32(tmp, z, Wv + e*DD*DD);
  #pragma unroll
  for (int d = 0; d < DD; ++d) vls[t*DD + d] = tmp[d];
  float q[DD];
  matvec32(q, z, Wq + e*DD*DD);
  __syncthreads();

  const float scale = 0.35355339059327373f;  // 1/sqrt(8)
  float s0[HH];
  #pragma unroll
  for (int hh = 0; hh < HH; ++hh) {
    float a = 0.f;
    #pragma unroll
    for (int d = 0; d < DH; ++d) a += q[hh*DH+d] * ws[WS_K0 + e*DD + hh*DH + d];
    s0[hh] = a * scale;
  }
  float wsum[HH] = {0.f, 0.f, 0.f, 0.f};
  float o[DD];
  #pragma unroll
  for (int d = 0; d < DD; ++d) o[d] = 0.f;

  // attention over same-expert keys (contiguous LDS range, broadcast reads)
  for (int j = beg; j < end; ++j) {
    const float* kr = &kls[j*DD];
    const float* vr = &vls[j*DD];
    float sc[HH];
    #pragma unroll
    for (int hh = 0; hh < HH; ++hh) {
      float a = 0.f;
      #pragma unroll
      for (int d = 0; d < DH; ++d) a += q[hh*DH+d] * kr[hh*DH+d];
      sc[hh] = a * scale;
    }
    #pragma unroll
    for (int hh = 0; hh < HH; ++hh) {
      float w = __expf(sc[hh]);
      wsum[hh] += w;
      #pragma unroll
      for (int d = 0; d < DH; ++d) o[hh*DH+d] += w * vr[hh*DH+d];
    }
  }
  // the (S - c_e) off-expert keys: constant score s0, constant value v0
  const int nmis = SS - (end - beg);
  #pragma unroll
  for (int hh = 0; hh < HH; ++hh) {
    float w = (float)nmis * __expf(s0[hh]);
    wsum[hh] += w;
    #pragma unroll
    for (int d = 0; d < DH; ++d) o[hh*DH+d] += w * ws[WS_V0 + e*DD + hh*DH + d];
    float inv = 1.0f / wsum[hh];
    #pragma unroll
    for (int d = 0; d < DH; ++d) o[hh*DH+d] *= inv;
  }

  matvec32(tmp, o, Wo + e*DD*DD);
  #pragma unroll
  for (int d = 0; d < DD; ++d) h[d] += tmp[d];

  // LN2
  m = 0.f;
  #pragma unroll
  for (int d = 0; d < DD; ++d) m += h[d];
  m *= (1.0f/DD);
  var = 0.f;
  #pragma unroll
  for (int d = 0; d < DD; ++d) { float df = h[d]-m; var += df*df; }
  var *= (1.0f/DD);
  rs = rsqrtf(var + 1e-5f);
  #pragma unroll
  for (int d = 0; d < DD; ++d) z[d] = (h[d]-m)*rs*g2[e*DD+d] + bb2[e*DD+d];

  // FFN in two 32-wide chunks of DFF to bound register pressure
  #pragma unroll
  for (int half = 0; half < 2; ++half) {
    float f[32];
    #pragma unroll
    for (int j = 0; j < 32; ++j) f[j] = 0.f;
    #pragma unroll
    for (int i = 0; i < DD; ++i) {
      float zz = z[i];
      const float4* row = (const float4*)(W1 + e*DD*DFF + i*DFF + half*32);
      #pragma unroll
      for (int j4 = 0; j4 < 8; ++j4) {
        float4 w = row[j4];
        f[j4*4+0] += zz*w.x; f[j4*4+1] += zz*w.y; f[j4*4+2] += zz*w.z; f[j4*4+3] += zz*w.w;
      }
    }
    #pragma unroll
    for (int j = 0; j < 32; ++j) f[j] = fmaxf(f[j] + b1[e*DFF + half*32 + j], 0.0f);
    #pragma unroll
    for (int j = 0; j < 32; ++j) {
      float ff = f[j];
      const float4* row = (const float4*)(W2 + e*DFF*DD + (half*32 + j)*DD);
      #pragma unroll
      for (int d4 = 0; d4 < 8; ++d4) {
        float4 w = row[d4];
        h[d4*4+0] += ff*w.x; h[d4*4+1] += ff*w.y; h[d4*4+2] += ff*w.z; h[d4*4+3] += ff*w.w;
      }
    }
  }
  #pragma unroll
  for (int d = 0; d < DD; ++d) h[d] += b2[e*DD+d];

  float* op = out + ((b*SS + s)*NCH + n)*DD;
  #pragma unroll
  for (int d = 0; d < DD; ++d) op[d] = h[d];
}

// ---------------------------------------------------------------------------
extern "C" void kernel_launch(void* const* d_in, const int* in_sizes, int n_in,
                              void* d_out, int out_size, void* d_ws, size_t ws_size,
                              hipStream_t stream) {
  (void)in_sizes; (void)n_in; (void)out_size; (void)ws_size;
  const float* x   = (const float*)d_in[0];
  const float* ox  = (const float*)d_in[1];
  const float* sW  = (const float*)d_in[2];
  const float* sb  = (const float*)d_in[3];
  const float* Wq  = (const float*)d_in[4];
  const float* Wk  = (const float*)d_in[5];
  const float* Wv  = (const float*)d_in[6];
  const float* Wo  = (const float*)d_in[7];
  const float* g1  = (const float*)d_in[8];
  const float* b1n = (const float*)d_in[9];
  const float* g2  = (const float*)d_in[10];
  const float* b2n = (const float*)d_in[11];
  const float* W1  = (const float*)d_in[12];
  const float* bf1 = (const float*)d_in[13];
  const float* W2  = (const float*)d_in[14];
  const float* bf2 = (const float*)d_in[15];
  float* out = (float*)d_out;
  float* ws  = (float*)d_ws;

  decomp_kernel<<<BB*NCH, 256, 0, stream>>>(x, ws);
  minmax_kernel<<<1, 256, 0, stream>>>(ox, ws);
  assign_kernel<<<BB, 256, 0, stream>>>(ox, ws);
  k0v0_kernel<<<1, 128, 0, stream>>>(sb, g1, b1n, Wk, Wv, ws);
  expert_kernel<<<BB*NCH, 256, 0, stream>>>(ws, sW, sb, Wq, Wk, Wv, Wo,
                                            g1, b1n, g2, b2n, W1, bf1, W2, bf2, out);
}